// Round 15
// baseline (296.340 us; speedup 1.0000x reference)
//
#include <hip/hip_runtime.h>
#include <hip/hip_bf16.h>

typedef __attribute__((ext_vector_type(8))) short bf16x8;
typedef __attribute__((ext_vector_type(4))) float f32x4;
typedef __attribute__((ext_vector_type(8))) unsigned short u16x8;

__device__ __forceinline__ unsigned short bf16_rne(float f) {
  union { float f; unsigned u; } c; c.f = f;
  unsigned u = c.u;
  return (unsigned short)((u + 0x7FFFu + ((u >> 16) & 1u)) >> 16);
}

__device__ __forceinline__ unsigned cvt_pk_bf16(float lo, float hi) {
  unsigned r;
  asm("v_cvt_pk_bf16_f32 %0, %1, %2" : "=v"(r) : "v"(lo), "v"(hi));
  return r;
}

__device__ __forceinline__ bf16x8 pack4(unsigned a, unsigned b, unsigned c, unsigned d) {
  union { unsigned u[4]; bf16x8 v; } t;
  t.u[0] = a; t.u[1] = b; t.u[2] = c; t.u[3] = d;
  return t.v;
}

// ===================== prep0 =====================
// fr<512: Dbf pack; fr<1536: w2^T pack; fr<1600: Gp/Bp k-partials (4096 thr);
// fr<1608: dsum closed form.
__global__ void fecam_prep0(const float* __restrict__ w1, const float* __restrict__ w2,
                            const float* __restrict__ g, const float* __restrict__ bb,
                            unsigned short* __restrict__ Dbf, unsigned short* __restrict__ w2p,
                            float* __restrict__ Gp, float* __restrict__ Bp,
                            float* __restrict__ dsum) {
  int t = blockIdx.x * 256 + threadIdx.x;
  int lane = t & 63;
  int fr = t >> 6;
  int l16 = lane & 15, lh = lane >> 4;
  if (fr < 512) {            // Dbf: D[k][l] pack for prep1 B-operand
    int ks = fr >> 5, lf = fr & 31;
    int l = lf * 16 + l16;
    unsigned short o[8];
#pragma unroll
    for (int j = 0; j < 8; ++j) {
      int k = ks * 32 + lh * 8 + j;
      int tt = (k * (2 * l + 1)) & 2047;
      o[j] = bf16_rne(2.0f * cosf((float)tt * 3.0679615757712823e-3f));
    }
    *(u16x8*)(Dbf + (size_t)t * 8) = *(u16x8*)o;
  } else if (fr < 1536) {    // w2^T pack (K=1024: 32 ksteps, N=512: 32 nfrags)
    int fr2 = fr - 512;
    int nf = fr2 & 31;
    int ks = fr2 >> 5;
    int n = nf * 16 + l16;
    unsigned short o[8];
#pragma unroll
    for (int j = 0; j < 8; ++j) {
      int k = ks * 32 + lh * 8 + j;
      o[j] = bf16_rne(w2[(size_t)n * 1024 + k]);
    }
    *(u16x8*)(w2p + ((size_t)fr2 * 64 + lane) * 8) = *(u16x8*)o;
  } else if (fr < 1600) {    // Gp/Bp partials: n x 4 k-groups of 128
    int t2 = (fr - 1536) * 64 + lane;    // 0..4095
    int n = t2 & 1023;
    int kg = t2 >> 10;                   // 0..3
    const float* wr = w1 + (size_t)n * 512 + kg * 128;
    const float* gr = g + kg * 128;
    const float* br = bb + kg * 128;
    float sg = 0.f, sb = 0.f;
#pragma unroll 4
    for (int k = 0; k < 128; k += 4) {
      float4 wv = *(const float4*)(wr + k);
      float4 gv = *(const float4*)(gr + k);
      float4 bv = *(const float4*)(br + k);
      sg += wv.x * gv.x + wv.y * gv.y + wv.z * gv.z + wv.w * gv.w;
      sb += wv.x * bv.x + wv.y * bv.y + wv.z * bv.z + wv.w * bv.w;
    }
    Gp[kg * 1024 + n] = sg;
    Bp[kg * 1024 + n] = sb;
  } else if (fr < 1608) {    // dsum[l] = 1 + (-1)^l * cot(pi(2l+1)/2048)
    int l = (fr - 1600) * 64 + lane;
    float a = (float)(2 * l + 1) * 1.5339807878856412e-3f;  // pi/2048
    float cs = cosf(a), sn = sinf(a);
    float ct = cs / sn;
    dsum[l] = 1.0f + ((l & 1) ? -ct : ct);
  }
}

// ===================== prep2: reduce Gp/Bp partials -> Gv/Bv =====================
__global__ void fecam_prep2(const float* __restrict__ Gp, const float* __restrict__ Bp,
                            float* __restrict__ Gv, float* __restrict__ Bv) {
  int n = blockIdx.x * 256 + threadIdx.x;   // 0..1023
  Gv[n] = Gp[n] + Gp[1024 + n] + Gp[2048 + n] + Gp[3072 + n];
  Bv[n] = Bp[n] + Bp[1024 + n] + Bp[2048 + n] + Bp[3072 + n];
}

// ===================== prep1: W1D = (w1 . g) @ D, packed =====================
__global__ void fecam_prep1(const float* __restrict__ w1, const float* __restrict__ g,
                            const unsigned short* __restrict__ Dbf,
                            unsigned short* __restrict__ W1Dp) {
  __shared__ float Cl[4][16][132];
  const int tid = threadIdx.x;
  const int lane = tid & 63;
  const int wv = tid >> 6;
  const int l16 = lane & 15, lh = lane >> 4;
  const int bi = blockIdx.x * 4 + wv;      // 0..255
  const int n0 = (bi >> 2) * 16;
  const int l0 = (bi & 3) * 128;

  f32x4 acc[8];
#pragma unroll
  for (int jn = 0; jn < 8; ++jn) acc[jn] = (f32x4){0.f, 0.f, 0.f, 0.f};

  for (int ks = 0; ks < 16; ++ks) {
    int kbase = ks * 32 + lh * 8;
    const float* wr = w1 + (size_t)(n0 + l16) * 512 + kbase;
    float4 wa = *(const float4*)(wr);
    float4 wb = *(const float4*)(wr + 4);
    float4 ga = *(const float4*)(g + kbase);
    float4 gb = *(const float4*)(g + kbase + 4);
    bf16x8 af = pack4(cvt_pk_bf16(wa.x * ga.x, wa.y * ga.y),
                      cvt_pk_bf16(wa.z * ga.z, wa.w * ga.w),
                      cvt_pk_bf16(wb.x * gb.x, wb.y * gb.y),
                      cvt_pk_bf16(wb.z * gb.z, wb.w * gb.w));
#pragma unroll
    for (int jn = 0; jn < 8; ++jn) {
      bf16x8 bf = *(const bf16x8*)(Dbf + (((size_t)ks * 32 + (l0 >> 4) + jn) * 64 + lane) * 8);
      acc[jn] = __builtin_amdgcn_mfma_f32_16x16x32_bf16(af, bf, acc[jn], 0, 0, 0);
    }
  }
#pragma unroll
  for (int jn = 0; jn < 8; ++jn)
#pragma unroll
    for (int q = 0; q < 4; ++q) Cl[wv][lh * 4 + q][jn * 16 + l16] = acc[jn][q];
  __syncthreads();
#pragma unroll
  for (int ks2 = 0; ks2 < 4; ++ks2) {
    float v[8];
#pragma unroll
    for (int j = 0; j < 8; ++j) v[j] = Cl[wv][l16][ks2 * 32 + lh * 8 + j];
    unsigned short o[8];
#pragma unroll
    for (int j = 0; j < 8; j += 2) {
      unsigned pk = cvt_pk_bf16(v[j], v[j + 1]);
      o[j] = (unsigned short)pk;
      o[j + 1] = (unsigned short)(pk >> 16);
    }
    size_t idx = (((size_t)((l0 >> 5) + ks2) * 64 + (n0 >> 4)) * 64 + lane) * 8;
    *(u16x8*)(W1Dp + idx) = *(u16x8*)o;
  }
}

// ===================== fused main: R14 base, G2 un-halved (wave = 64x64,
// acc2[4][4]; viable because acc3 is scoped after bar3). G2 A-LDS traffic
// halves; one h-epilogue. Wave w writes h frags 2w,2w+1 (w<8 -> bufB,
// w>=8 -> bufA after bar2). G3 read pattern unchanged. =====================
__global__ __launch_bounds__(1024, 4) void fecam_main(
    const float* __restrict__ x, const float* __restrict__ gamma, const float* __restrict__ beta,
    const unsigned short* __restrict__ W1Dp, const unsigned short* __restrict__ w2p,
    const float* __restrict__ Gv, const float* __restrict__ Bv,
    const float* __restrict__ dsum, float* __restrict__ out) {
  extern __shared__ char smem[];
  char* bufA = smem;                     // 64KB: x frags -> h frags 16..31
  char* bufB = smem + 65536;             // 64KB: h frags 0..15
  float* ra = (float*)(smem + 131072);   // [64] sum x
  float* rb = ra + 64;                   // sum x^2
  float* rc = rb + 64;                   // sum x*dsum
  float* rs2 = rc + 64;                  // LN2 sums
  float* rq2 = rs2 + 64;                 // LN2 sumsq

  const int tid = threadIdx.x;
  const int lane = tid & 63;
  const int w = tid >> 6;            // wave 0..15
  const int l16 = lane & 15, lh = lane >> 4;
  const int b = blockIdx.x >> 3;
  const int c0 = (blockIdx.x & 7) * 64;

  if (tid < 320) ra[tid] = 0.0f;     // zero all 5 stat arrays
  __syncthreads();                   // bar0

  // ---- stage x -> bufA fragment-linear (wave w owns frag ks=w); row stats ----
  {
    const int cc = lane;             // row (c offset)
    const float* xb = x + ((size_t)b * 512) * 512 + c0 + cc;
    char* xwb = bufA + w * 4096 + (cc >> 4) * 1024 + (cc & 15) * 16;
    float s1 = 0.f, s2 = 0.f, sdp = 0.f;
#pragma unroll
    for (int gblk = 0; gblk < 4; ++gblk) {
      int k0 = w * 32 + gblk * 8;    // 8 consecutive k
      float4 d0 = *(const float4*)(dsum + k0);
      float4 d1 = *(const float4*)(dsum + k0 + 4);
      float v[8];
#pragma unroll
      for (int j = 0; j < 8; ++j) {
        v[j] = xb[(size_t)(k0 + j) * 512];
        s1 += v[j];
        s2 += v[j] * v[j];
      }
      sdp += v[0] * d0.x + v[1] * d0.y + v[2] * d0.z + v[3] * d0.w +
             v[4] * d1.x + v[5] * d1.y + v[6] * d1.z + v[7] * d1.w;
      unsigned short o[8];
#pragma unroll
      for (int j = 0; j < 8; j += 2) {
        unsigned pk = cvt_pk_bf16(v[j], v[j + 1]);
        o[j] = (unsigned short)pk;
        o[j + 1] = (unsigned short)(pk >> 16);
      }
      *(u16x8*)(xwb + gblk * 256) = *(u16x8*)o;
    }
    atomicAdd(&ra[cc], s1);
    atomicAdd(&rb[cc], s2);
    atomicAdd(&rc[cc], sdp);
  }

  // per-wave constants
  float g_[2], b_[2], Gn_[4], Bn_[4];
#pragma unroll
  for (int jj = 0; jj < 2; ++jj) {
    g_[jj] = gamma[w * 32 + jj * 16 + l16];
    b_[jj] = beta[w * 32 + jj * 16 + l16];
  }
#pragma unroll
  for (int jj = 0; jj < 4; ++jj) {
    int n = w * 64 + jj * 16 + l16;
    Gn_[jj] = Gv[n];
    Bn_[jj] = Bv[n];
  }

  __syncthreads();                   // bar1: x + stats visible

  const char* ards = smem + lane * 16;          // A-read base (x / h frags 16..31)
  const char* brds = bufB + lane * 16;          // A-read base (h frags 0..15)

  // ======== G2 single pass: wave = 64 rows x 64 cols (n = w*64..w*64+63) ========
  {
    f32x4 acc2[4][4];
#pragma unroll
    for (int i = 0; i < 4; ++i)
#pragma unroll
      for (int jj = 0; jj < 4; ++jj) acc2[i][jj] = (f32x4){0.f, 0.f, 0.f, 0.f};

#pragma unroll 2
    for (int ks = 0; ks < 16; ++ks) {
      bf16x8 af[4];
#pragma unroll
      for (int i = 0; i < 4; ++i)
        af[i] = *(const bf16x8*)(ards + (ks * 4 + i) * 1024);
#pragma unroll
      for (int jj = 0; jj < 4; ++jj) {
        bf16x8 bf = *(const bf16x8*)(
            W1Dp + (((size_t)ks * 64 + w * 4 + jj) * 64 + lane) * 8);
#pragma unroll
        for (int i = 0; i < 4; ++i)
          acc2[i][jj] = __builtin_amdgcn_mfma_f32_16x16x32_bf16(af[i], bf, acc2[i][jj], 0, 0, 0);
      }
    }
    __syncthreads();                 // bar2: all x reads done; bufA reusable

    // h epilogue (once): wave w -> frags 2w (jj<2) and 2w+1 (jj>=2)
    char* hb = (w < 8) ? (bufB + (size_t)(2 * w) * 4096)
                       : (bufA + (size_t)(2 * w - 16) * 4096);
    char* hwb = hb + (l16 >> 3) * 256 + lh * 64 + (l16 & 7) * 2;
    float mu_[4][4], rstd_[4][4];
#pragma unroll
    for (int i = 0; i < 4; ++i)
#pragma unroll
      for (int q = 0; q < 4; ++q) {
        int r = i * 16 + lh * 4 + q;
        float s1 = ra[r], s2v = rb[r];
        float mu = rc[r] * (1.0f / 512.0f);
        float var = s1 * s1 * (1.0f / 256.0f) + 2.0f * s2v - mu * mu;
        mu_[i][q] = mu;
        rstd_[i][q] = rsqrtf(var + 1e-6f);
      }
#pragma unroll
    for (int i = 0; i < 4; ++i)
#pragma unroll
      for (int jj = 0; jj < 4; ++jj)
#pragma unroll
        for (int q = 0; q < 4; ++q) {
          float c00 = fmaf(-rstd_[i][q] * mu_[i][q], Gn_[jj], Bn_[jj]);
          float v0 = fmaxf(fmaf(acc2[i][jj][q], rstd_[i][q], c00), 0.0f);
          *(unsigned short*)(hwb + (jj >> 1) * 4096 + i * 1024 + (jj & 1) * 512 + q * 16) =
              bf16_rne(v0);
        }
  }
  __syncthreads();                   // bar3: h complete

  // ======== G3 (acc3 lives only from here): fw = h @ w2^T, K=1024 ========
  {
    f32x4 acc3[4][2];
#pragma unroll
    for (int i = 0; i < 4; ++i)
#pragma unroll
      for (int jj = 0; jj < 2; ++jj) acc3[i][jj] = (f32x4){0.f, 0.f, 0.f, 0.f};

#pragma unroll 2
    for (int ks = 0; ks < 16; ++ks) {
      bf16x8 af[4];
#pragma unroll
      for (int i = 0; i < 4; ++i)
        af[i] = *(const bf16x8*)(brds + (ks * 4 + i) * 1024);
#pragma unroll
      for (int jj = 0; jj < 2; ++jj) {
        bf16x8 bf = *(const bf16x8*)(w2p + (((size_t)ks * 32 + w * 2 + jj) * 64 + lane) * 8);
#pragma unroll
        for (int i = 0; i < 4; ++i)
          acc3[i][jj] = __builtin_amdgcn_mfma_f32_16x16x32_bf16(af[i], bf, acc3[i][jj], 0, 0, 0);
      }
    }
#pragma unroll 2
    for (int ks = 0; ks < 16; ++ks) {
      bf16x8 af[4];
#pragma unroll
      for (int i = 0; i < 4; ++i)
        af[i] = *(const bf16x8*)(ards + (ks * 4 + i) * 1024);
#pragma unroll
      for (int jj = 0; jj < 2; ++jj) {
        bf16x8 bf = *(const bf16x8*)(
            w2p + (((size_t)(16 + ks) * 32 + w * 2 + jj) * 64 + lane) * 8);
#pragma unroll
        for (int i = 0; i < 4; ++i)
          acc3[i][jj] = __builtin_amdgcn_mfma_f32_16x16x32_bf16(af[i], bf, acc3[i][jj], 0, 0, 0);
      }
    }

    // ---- sigmoid ----
#pragma unroll
    for (int i = 0; i < 4; ++i)
#pragma unroll
      for (int jj = 0; jj < 2; ++jj)
#pragma unroll
        for (int q = 0; q < 4; ++q)
          acc3[i][jj][q] = 1.0f / (1.0f + __expf(-acc3[i][jj][q]));

    // ---- LN2 stats ----
#pragma unroll
    for (int i = 0; i < 4; ++i) {
#pragma unroll
      for (int q = 0; q < 4; ++q) {
        float s = acc3[i][0][q] + acc3[i][1][q];
        float ss = acc3[i][0][q] * acc3[i][0][q] + acc3[i][1][q] * acc3[i][1][q];
#pragma unroll
        for (int m = 1; m <= 8; m <<= 1) {
          s += __shfl_xor(s, m);
          ss += __shfl_xor(ss, m);
        }
        if (l16 == 0) {
          atomicAdd(&rs2[i * 16 + lh * 4 + q], s);
          atomicAdd(&rq2[i * 16 + lh * 4 + q], ss);
        }
      }
    }
    __syncthreads();                 // bar4

    // ---- LN2 normalize, multiply by xp, store out[b][col][c0+r] ----
#pragma unroll
    for (int i = 0; i < 4; ++i) {
      float mu_[4], rstd_[4];
#pragma unroll
      for (int q = 0; q < 4; ++q) {
        int r = i * 16 + lh * 4 + q;
        float mu = rs2[r] * (1.0f / 512.0f);
        float var = rq2[r] * (1.0f / 512.0f) - mu * mu;
        mu_[q] = mu;
        rstd_[q] = rsqrtf(var + 1e-6f);
      }
#pragma unroll
      for (int jj = 0; jj < 2; ++jj) {
        int col = w * 32 + jj * 16 + l16;
        size_t base = ((size_t)b * 512 + col) * 512 + c0 + i * 16 + lh * 4;
        float4 xv = *(const float4*)(x + base);
        float4 ov;
#pragma unroll
        for (int q = 0; q < 4; ++q) {
          float fn = (acc3[i][jj][q] - mu_[q]) * rstd_[q] * g_[jj] + b_[jj];
          (&ov.x)[q] = (&xv.x)[q] * fn;
        }
        *(float4*)(out + base) = ov;
      }
    }
  }
}

extern "C" void kernel_launch(void* const* d_in, const int* in_sizes, int n_in,
                              void* d_out, int out_size, void* d_ws, size_t ws_size,
                              hipStream_t stream) {
  const float* x = (const float*)d_in[0];
  const float* gamma = (const float*)d_in[1];
  const float* beta = (const float*)d_in[2];
  const float* w1 = (const float*)d_in[3];
  const float* w2 = (const float*)d_in[4];

  unsigned short* w2p = (unsigned short*)d_ws;       // 524288 bf16
  unsigned short* W1Dp = w2p + 524288;               // 524288 bf16
  unsigned short* Dbf = W1Dp + 524288;               // 262144 bf16
  float* Gp = (float*)(Dbf + 262144);                // 4096 f32
  float* Bp = Gp + 4096;                             // 4096 f32
  float* dsum = Bp + 4096;                           // 512 f32
  float* Gv = dsum + 512;                            // 1024 f32
  float* Bv = Gv + 1024;                             // 1024 f32

  fecam_prep0<<<402, 256, 0, stream>>>(w1, w2, gamma, beta, Dbf, w2p, Gp, Bp, dsum);
  fecam_prep2<<<4, 256, 0, stream>>>(Gp, Bp, Gv, Bv);
  fecam_prep1<<<64, 256, 0, stream>>>(w1, gamma, Dbf, W1Dp);
  fecam_main<<<1024, 1024, 132416, stream>>>(x, gamma, beta, W1Dp, w2p, Gv, Bv, dsum,
                                             (float*)d_out);
}

// Round 16
// 285.257 us; speedup vs baseline: 1.0389x; 1.0389x over previous
//
#include <hip/hip_runtime.h>
#include <hip/hip_bf16.h>

typedef __attribute__((ext_vector_type(8))) short bf16x8;
typedef __attribute__((ext_vector_type(4))) float f32x4;
typedef __attribute__((ext_vector_type(8))) unsigned short u16x8;

__device__ __forceinline__ unsigned short bf16_rne(float f) {
  union { float f; unsigned u; } c; c.f = f;
  unsigned u = c.u;
  return (unsigned short)((u + 0x7FFFu + ((u >> 16) & 1u)) >> 16);
}

__device__ __forceinline__ unsigned cvt_pk_bf16(float lo, float hi) {
  unsigned r;
  asm("v_cvt_pk_bf16_f32 %0, %1, %2" : "=v"(r) : "v"(lo), "v"(hi));
  return r;
}

__device__ __forceinline__ bf16x8 pack4(unsigned a, unsigned b, unsigned c, unsigned d) {
  union { unsigned u[4]; bf16x8 v; } t;
  t.u[0] = a; t.u[1] = b; t.u[2] = c; t.u[3] = d;
  return t.v;
}

// ===================== prep0 =====================
// fr<512: Dbf pack; fr<1536: w2^T pack; fr<1600: Gp/Bp k-partials (4096 thr);
// fr<1608: dsum closed form.
__global__ void fecam_prep0(const float* __restrict__ w1, const float* __restrict__ w2,
                            const float* __restrict__ g, const float* __restrict__ bb,
                            unsigned short* __restrict__ Dbf, unsigned short* __restrict__ w2p,
                            float* __restrict__ Gp, float* __restrict__ Bp,
                            float* __restrict__ dsum) {
  int t = blockIdx.x * 256 + threadIdx.x;
  int lane = t & 63;
  int fr = t >> 6;
  int l16 = lane & 15, lh = lane >> 4;
  if (fr < 512) {            // Dbf: D[k][l] pack for prep1 B-operand
    int ks = fr >> 5, lf = fr & 31;
    int l = lf * 16 + l16;
    unsigned short o[8];
#pragma unroll
    for (int j = 0; j < 8; ++j) {
      int k = ks * 32 + lh * 8 + j;
      int tt = (k * (2 * l + 1)) & 2047;
      o[j] = bf16_rne(2.0f * cosf((float)tt * 3.0679615757712823e-3f));
    }
    *(u16x8*)(Dbf + (size_t)t * 8) = *(u16x8*)o;
  } else if (fr < 1536) {    // w2^T pack (K=1024: 32 ksteps, N=512: 32 nfrags)
    int fr2 = fr - 512;
    int nf = fr2 & 31;
    int ks = fr2 >> 5;
    int n = nf * 16 + l16;
    unsigned short o[8];
#pragma unroll
    for (int j = 0; j < 8; ++j) {
      int k = ks * 32 + lh * 8 + j;
      o[j] = bf16_rne(w2[(size_t)n * 1024 + k]);
    }
    *(u16x8*)(w2p + ((size_t)fr2 * 64 + lane) * 8) = *(u16x8*)o;
  } else if (fr < 1600) {    // Gp/Bp partials: n x 4 k-groups of 128
    int t2 = (fr - 1536) * 64 + lane;    // 0..4095
    int n = t2 & 1023;
    int kg = t2 >> 10;                   // 0..3
    const float* wr = w1 + (size_t)n * 512 + kg * 128;
    const float* gr = g + kg * 128;
    const float* br = bb + kg * 128;
    float sg = 0.f, sb = 0.f;
#pragma unroll 4
    for (int k = 0; k < 128; k += 4) {
      float4 wv = *(const float4*)(wr + k);
      float4 gv = *(const float4*)(gr + k);
      float4 bv = *(const float4*)(br + k);
      sg += wv.x * gv.x + wv.y * gv.y + wv.z * gv.z + wv.w * gv.w;
      sb += wv.x * bv.x + wv.y * bv.y + wv.z * bv.z + wv.w * bv.w;
    }
    Gp[kg * 1024 + n] = sg;
    Bp[kg * 1024 + n] = sb;
  } else if (fr < 1608) {    // dsum[l] = 1 + (-1)^l * cot(pi(2l+1)/2048)
    int l = (fr - 1600) * 64 + lane;
    float a = (float)(2 * l + 1) * 1.5339807878856412e-3f;  // pi/2048
    float cs = cosf(a), sn = sinf(a);
    float ct = cs / sn;
    dsum[l] = 1.0f + ((l & 1) ? -ct : ct);
  }
}

// ===================== prep2: reduce Gp/Bp partials -> Gv/Bv =====================
__global__ void fecam_prep2(const float* __restrict__ Gp, const float* __restrict__ Bp,
                            float* __restrict__ Gv, float* __restrict__ Bv) {
  int n = blockIdx.x * 256 + threadIdx.x;   // 0..1023
  Gv[n] = Gp[n] + Gp[1024 + n] + Gp[2048 + n] + Gp[3072 + n];
  Bv[n] = Bp[n] + Bp[1024 + n] + Bp[2048 + n] + Bp[3072 + n];
}

// ===================== prep1: W1D = (w1 . g) @ D, packed =====================
__global__ void fecam_prep1(const float* __restrict__ w1, const float* __restrict__ g,
                            const unsigned short* __restrict__ Dbf,
                            unsigned short* __restrict__ W1Dp) {
  __shared__ float Cl[4][16][132];
  const int tid = threadIdx.x;
  const int lane = tid & 63;
  const int wv = tid >> 6;
  const int l16 = lane & 15, lh = lane >> 4;
  const int bi = blockIdx.x * 4 + wv;      // 0..255
  const int n0 = (bi >> 2) * 16;
  const int l0 = (bi & 3) * 128;

  f32x4 acc[8];
#pragma unroll
  for (int jn = 0; jn < 8; ++jn) acc[jn] = (f32x4){0.f, 0.f, 0.f, 0.f};

  for (int ks = 0; ks < 16; ++ks) {
    int kbase = ks * 32 + lh * 8;
    const float* wr = w1 + (size_t)(n0 + l16) * 512 + kbase;
    float4 wa = *(const float4*)(wr);
    float4 wb = *(const float4*)(wr + 4);
    float4 ga = *(const float4*)(g + kbase);
    float4 gb = *(const float4*)(g + kbase + 4);
    bf16x8 af = pack4(cvt_pk_bf16(wa.x * ga.x, wa.y * ga.y),
                      cvt_pk_bf16(wa.z * ga.z, wa.w * ga.w),
                      cvt_pk_bf16(wb.x * gb.x, wb.y * gb.y),
                      cvt_pk_bf16(wb.z * gb.z, wb.w * gb.w));
#pragma unroll
    for (int jn = 0; jn < 8; ++jn) {
      bf16x8 bf = *(const bf16x8*)(Dbf + (((size_t)ks * 32 + (l0 >> 4) + jn) * 64 + lane) * 8);
      acc[jn] = __builtin_amdgcn_mfma_f32_16x16x32_bf16(af, bf, acc[jn], 0, 0, 0);
    }
  }
#pragma unroll
  for (int jn = 0; jn < 8; ++jn)
#pragma unroll
    for (int q = 0; q < 4; ++q) Cl[wv][lh * 4 + q][jn * 16 + l16] = acc[jn][q];
  __syncthreads();
#pragma unroll
  for (int ks2 = 0; ks2 < 4; ++ks2) {
    float v[8];
#pragma unroll
    for (int j = 0; j < 8; ++j) v[j] = Cl[wv][l16][ks2 * 32 + lh * 8 + j];
    unsigned short o[8];
#pragma unroll
    for (int j = 0; j < 8; j += 2) {
      unsigned pk = cvt_pk_bf16(v[j], v[j + 1]);
      o[j] = (unsigned short)pk;
      o[j + 1] = (unsigned short)(pk >> 16);
    }
    size_t idx = (((size_t)((l0 >> 5) + ks2) * 64 + (n0 >> 4)) * 64 + lane) * 8;
    *(u16x8*)(W1Dp + idx) = *(u16x8*)o;
  }
}

// ===================== fused main (R14 structure + s_setprio around MFMA loops) =====================
__global__ __launch_bounds__(1024, 4) void fecam_main(
    const float* __restrict__ x, const float* __restrict__ gamma, const float* __restrict__ beta,
    const unsigned short* __restrict__ W1Dp, const unsigned short* __restrict__ w2p,
    const float* __restrict__ Gv, const float* __restrict__ Bv,
    const float* __restrict__ dsum, float* __restrict__ out) {
  extern __shared__ char smem[];
  char* bufA = smem;                     // 64KB: x frags -> h half1 frags
  char* bufB = smem + 65536;             // 64KB: h half0 frags
  float* ra = (float*)(smem + 131072);   // [64] sum x
  float* rb = ra + 64;                   // sum x^2
  float* rc = rb + 64;                   // sum x*dsum
  float* rs2 = rc + 64;                  // LN2 sums
  float* rq2 = rs2 + 64;                 // LN2 sumsq

  const int tid = threadIdx.x;
  const int lane = tid & 63;
  const int w = tid >> 6;            // wave 0..15
  const int l16 = lane & 15, lh = lane >> 4;
  const int b = blockIdx.x >> 3;
  const int c0 = (blockIdx.x & 7) * 64;

  if (tid < 320) ra[tid] = 0.0f;     // zero all 5 stat arrays
  __syncthreads();                   // bar0

  // ---- stage x -> bufA fragment-linear (wave w owns frag ks=w); row stats ----
  {
    const int cc = lane;             // row (c offset)
    const float* xb = x + ((size_t)b * 512) * 512 + c0 + cc;
    char* xwb = bufA + w * 4096 + (cc >> 4) * 1024 + (cc & 15) * 16;
    float s1 = 0.f, s2 = 0.f, sdp = 0.f;
#pragma unroll
    for (int gblk = 0; gblk < 4; ++gblk) {
      int k0 = w * 32 + gblk * 8;    // 8 consecutive k
      float4 d0 = *(const float4*)(dsum + k0);
      float4 d1 = *(const float4*)(dsum + k0 + 4);
      float v[8];
#pragma unroll
      for (int j = 0; j < 8; ++j) {
        v[j] = xb[(size_t)(k0 + j) * 512];
        s1 += v[j];
        s2 += v[j] * v[j];
      }
      sdp += v[0] * d0.x + v[1] * d0.y + v[2] * d0.z + v[3] * d0.w +
             v[4] * d1.x + v[5] * d1.y + v[6] * d1.z + v[7] * d1.w;
      unsigned short o[8];
#pragma unroll
      for (int j = 0; j < 8; j += 2) {
        unsigned pk = cvt_pk_bf16(v[j], v[j + 1]);
        o[j] = (unsigned short)pk;
        o[j + 1] = (unsigned short)(pk >> 16);
      }
      *(u16x8*)(xwb + gblk * 256) = *(u16x8*)o;
    }
    atomicAdd(&ra[cc], s1);
    atomicAdd(&rb[cc], s2);
    atomicAdd(&rc[cc], sdp);
  }

  // per-wave constants (direct loads — spill-free per R11/R14)
  float g_[2], b_[2], Gn_[2][2], Bn_[2][2];
#pragma unroll
  for (int jj = 0; jj < 2; ++jj) {
    g_[jj] = gamma[w * 32 + jj * 16 + l16];
    b_[jj] = beta[w * 32 + jj * 16 + l16];
  }
#pragma unroll
  for (int hh = 0; hh < 2; ++hh)
#pragma unroll
    for (int jj = 0; jj < 2; ++jj) {
      int n = hh * 512 + w * 32 + jj * 16 + l16;
      Gn_[hh][jj] = Gv[n];
      Bn_[hh][jj] = Bv[n];
    }

  __syncthreads();                   // bar1: x + stats visible

  const char* ards = smem + lane * 16;          // A-read base (x / h1 frags)
  const char* brds = bufB + lane * 16;          // A-read base (h0 frags)

  // ======== G2: two 512-col halves, wave = 64 rows x 32 cols ========
#pragma unroll
  for (int half = 0; half < 2; ++half) {
    f32x4 acc2[4][2];
#pragma unroll
    for (int i = 0; i < 4; ++i)
#pragma unroll
      for (int jj = 0; jj < 2; ++jj) acc2[i][jj] = (f32x4){0.f, 0.f, 0.f, 0.f};

    __builtin_amdgcn_s_setprio(1);
#pragma unroll 2
    for (int ks = 0; ks < 16; ++ks) {
      bf16x8 af[4];
#pragma unroll
      for (int i = 0; i < 4; ++i)
        af[i] = *(const bf16x8*)(ards + (ks * 4 + i) * 1024);
#pragma unroll
      for (int jj = 0; jj < 2; ++jj) {
        bf16x8 bf = *(const bf16x8*)(
            W1Dp + (((size_t)ks * 64 + half * 32 + w * 2 + jj) * 64 + lane) * 8);
#pragma unroll
        for (int i = 0; i < 4; ++i)
          acc2[i][jj] = __builtin_amdgcn_mfma_f32_16x16x32_bf16(af[i], bf, acc2[i][jj], 0, 0, 0);
      }
    }
    __builtin_amdgcn_s_setprio(0);

    if (half == 1) __syncthreads();  // bar2: all x reads done before overwrite

    // h epilogue -> fragment-linear writes (frag ks = half*16 + w)
    char* hwb = (half ? bufA : bufB) + w * 4096 + (l16 >> 3) * 256 + lh * 64 + (l16 & 7) * 2;
    float mu_[4][4], rstd_[4][4];
#pragma unroll
    for (int i = 0; i < 4; ++i)
#pragma unroll
      for (int q = 0; q < 4; ++q) {
        int r = i * 16 + lh * 4 + q;
        float s1 = ra[r], s2v = rb[r];
        float mu = rc[r] * (1.0f / 512.0f);
        float var = s1 * s1 * (1.0f / 256.0f) + 2.0f * s2v - mu * mu;
        mu_[i][q] = mu;
        rstd_[i][q] = rsqrtf(var + 1e-6f);
      }
#pragma unroll
    for (int i = 0; i < 4; ++i)
#pragma unroll
      for (int jj = 0; jj < 2; ++jj)
#pragma unroll
        for (int q = 0; q < 4; ++q) {
          float c00 = fmaf(-rstd_[i][q] * mu_[i][q], Gn_[half][jj], Bn_[half][jj]);
          float v0 = fmaxf(fmaf(acc2[i][jj][q], rstd_[i][q], c00), 0.0f);
          *(unsigned short*)(hwb + i * 1024 + jj * 512 + q * 16) = bf16_rne(v0);
        }
  }
  __syncthreads();                   // bar3: h complete

  // ======== G3 (acc3 lives only from here): fw = h @ w2^T, K=1024 ========
  {
    f32x4 acc3[4][2];
#pragma unroll
    for (int i = 0; i < 4; ++i)
#pragma unroll
      for (int jj = 0; jj < 2; ++jj) acc3[i][jj] = (f32x4){0.f, 0.f, 0.f, 0.f};

    __builtin_amdgcn_s_setprio(1);
#pragma unroll 2
    for (int ks = 0; ks < 16; ++ks) {
      bf16x8 af[4];
#pragma unroll
      for (int i = 0; i < 4; ++i)
        af[i] = *(const bf16x8*)(brds + (ks * 4 + i) * 1024);
#pragma unroll
      for (int jj = 0; jj < 2; ++jj) {
        bf16x8 bf = *(const bf16x8*)(w2p + (((size_t)ks * 32 + w * 2 + jj) * 64 + lane) * 8);
#pragma unroll
        for (int i = 0; i < 4; ++i)
          acc3[i][jj] = __builtin_amdgcn_mfma_f32_16x16x32_bf16(af[i], bf, acc3[i][jj], 0, 0, 0);
      }
    }
#pragma unroll 2
    for (int ks = 0; ks < 16; ++ks) {
      bf16x8 af[4];
#pragma unroll
      for (int i = 0; i < 4; ++i)
        af[i] = *(const bf16x8*)(ards + (ks * 4 + i) * 1024);
#pragma unroll
      for (int jj = 0; jj < 2; ++jj) {
        bf16x8 bf = *(const bf16x8*)(
            w2p + (((size_t)(16 + ks) * 32 + w * 2 + jj) * 64 + lane) * 8);
#pragma unroll
        for (int i = 0; i < 4; ++i)
          acc3[i][jj] = __builtin_amdgcn_mfma_f32_16x16x32_bf16(af[i], bf, acc3[i][jj], 0, 0, 0);
      }
    }
    __builtin_amdgcn_s_setprio(0);

    // ---- sigmoid ----
#pragma unroll
    for (int i = 0; i < 4; ++i)
#pragma unroll
      for (int jj = 0; jj < 2; ++jj)
#pragma unroll
        for (int q = 0; q < 4; ++q)
          acc3[i][jj][q] = 1.0f / (1.0f + __expf(-acc3[i][jj][q]));

    // ---- LN2 stats ----
#pragma unroll
    for (int i = 0; i < 4; ++i) {
#pragma unroll
      for (int q = 0; q < 4; ++q) {
        float s = acc3[i][0][q] + acc3[i][1][q];
        float ss = acc3[i][0][q] * acc3[i][0][q] + acc3[i][1][q] * acc3[i][1][q];
#pragma unroll
        for (int m = 1; m <= 8; m <<= 1) {
          s += __shfl_xor(s, m);
          ss += __shfl_xor(ss, m);
        }
        if (l16 == 0) {
          atomicAdd(&rs2[i * 16 + lh * 4 + q], s);
          atomicAdd(&rq2[i * 16 + lh * 4 + q], ss);
        }
      }
    }
    __syncthreads();                 // bar4

    // ---- LN2 normalize, multiply by xp, store out[b][col][c0+r] ----
#pragma unroll
    for (int i = 0; i < 4; ++i) {
      float mu_[4], rstd_[4];
#pragma unroll
      for (int q = 0; q < 4; ++q) {
        int r = i * 16 + lh * 4 + q;
        float mu = rs2[r] * (1.0f / 512.0f);
        float var = rq2[r] * (1.0f / 512.0f) - mu * mu;
        mu_[q] = mu;
        rstd_[q] = rsqrtf(var + 1e-6f);
      }
#pragma unroll
      for (int jj = 0; jj < 2; ++jj) {
        int col = w * 32 + jj * 16 + l16;
        size_t base = ((size_t)b * 512 + col) * 512 + c0 + i * 16 + lh * 4;
        float4 xv = *(const float4*)(x + base);
        float4 ov;
#pragma unroll
        for (int q = 0; q < 4; ++q) {
          float fn = (acc3[i][jj][q] - mu_[q]) * rstd_[q] * g_[jj] + b_[jj];
          (&ov.x)[q] = (&xv.x)[q] * fn;
        }
        *(float4*)(out + base) = ov;
      }
    }
  }
}

extern "C" void kernel_launch(void* const* d_in, const int* in_sizes, int n_in,
                              void* d_out, int out_size, void* d_ws, size_t ws_size,
                              hipStream_t stream) {
  const float* x = (const float*)d_in[0];
  const float* gamma = (const float*)d_in[1];
  const float* beta = (const float*)d_in[2];
  const float* w1 = (const float*)d_in[3];
  const float* w2 = (const float*)d_in[4];

  unsigned short* w2p = (unsigned short*)d_ws;       // 524288 bf16
  unsigned short* W1Dp = w2p + 524288;               // 524288 bf16
  unsigned short* Dbf = W1Dp + 524288;               // 262144 bf16
  float* Gp = (float*)(Dbf + 262144);                // 4096 f32
  float* Bp = Gp + 4096;                             // 4096 f32
  float* dsum = Bp + 4096;                           // 512 f32
  float* Gv = dsum + 512;                            // 1024 f32
  float* Bv = Gv + 1024;                             // 1024 f32

  fecam_prep0<<<402, 256, 0, stream>>>(w1, w2, gamma, beta, Dbf, w2p, Gp, Bp, dsum);
  fecam_prep2<<<4, 256, 0, stream>>>(Gp, Bp, Gv, Bv);
  fecam_prep1<<<64, 256, 0, stream>>>(w1, gamma, Dbf, W1Dp);
  fecam_main<<<1024, 1024, 132416, stream>>>(x, gamma, beta, W1Dp, w2p, Gv, Bv, dsum,
                                             (float*)d_out);
}

// Round 17
// 261.730 us; speedup vs baseline: 1.1322x; 1.0899x over previous
//
#include <hip/hip_runtime.h>
#include <hip/hip_bf16.h>

typedef __attribute__((ext_vector_type(8))) short bf16x8;
typedef __attribute__((ext_vector_type(4))) float f32x4;
typedef __attribute__((ext_vector_type(8))) unsigned short u16x8;

__device__ __forceinline__ unsigned short bf16_rne(float f) {
  union { float f; unsigned u; } c; c.f = f;
  unsigned u = c.u;
  return (unsigned short)((u + 0x7FFFu + ((u >> 16) & 1u)) >> 16);
}

__device__ __forceinline__ unsigned cvt_pk_bf16(float lo, float hi) {
  unsigned r;
  asm("v_cvt_pk_bf16_f32 %0, %1, %2" : "=v"(r) : "v"(lo), "v"(hi));
  return r;
}

__device__ __forceinline__ bf16x8 pack4(unsigned a, unsigned b, unsigned c, unsigned d) {
  union { unsigned u[4]; bf16x8 v; } t;
  t.u[0] = a; t.u[1] = b; t.u[2] = c; t.u[3] = d;
  return t.v;
}

// ===================== prep0 =====================
// fr<512: Dbf pack; fr<1536: w2^T pack; fr<1600: Gp/Bp k-partials (4096 thr);
// fr<1608: dsum closed form.
__global__ void fecam_prep0(const float* __restrict__ w1, const float* __restrict__ w2,
                            const float* __restrict__ g, const float* __restrict__ bb,
                            unsigned short* __restrict__ Dbf, unsigned short* __restrict__ w2p,
                            float* __restrict__ Gp, float* __restrict__ Bp,
                            float* __restrict__ dsum) {
  int t = blockIdx.x * 256 + threadIdx.x;
  int lane = t & 63;
  int fr = t >> 6;
  int l16 = lane & 15, lh = lane >> 4;
  if (fr < 512) {            // Dbf: D[k][l] pack for prep1 B-operand
    int ks = fr >> 5, lf = fr & 31;
    int l = lf * 16 + l16;
    unsigned short o[8];
#pragma unroll
    for (int j = 0; j < 8; ++j) {
      int k = ks * 32 + lh * 8 + j;
      int tt = (k * (2 * l + 1)) & 2047;
      o[j] = bf16_rne(2.0f * cosf((float)tt * 3.0679615757712823e-3f));
    }
    *(u16x8*)(Dbf + (size_t)t * 8) = *(u16x8*)o;
  } else if (fr < 1536) {    // w2^T pack (K=1024: 32 ksteps, N=512: 32 nfrags)
    int fr2 = fr - 512;
    int nf = fr2 & 31;
    int ks = fr2 >> 5;
    int n = nf * 16 + l16;
    unsigned short o[8];
#pragma unroll
    for (int j = 0; j < 8; ++j) {
      int k = ks * 32 + lh * 8 + j;
      o[j] = bf16_rne(w2[(size_t)n * 1024 + k]);
    }
    *(u16x8*)(w2p + ((size_t)fr2 * 64 + lane) * 8) = *(u16x8*)o;
  } else if (fr < 1600) {    // Gp/Bp partials: n x 4 k-groups of 128
    int t2 = (fr - 1536) * 64 + lane;    // 0..4095
    int n = t2 & 1023;
    int kg = t2 >> 10;                   // 0..3
    const float* wr = w1 + (size_t)n * 512 + kg * 128;
    const float* gr = g + kg * 128;
    const float* br = bb + kg * 128;
    float sg = 0.f, sb = 0.f;
#pragma unroll 4
    for (int k = 0; k < 128; k += 4) {
      float4 wv = *(const float4*)(wr + k);
      float4 gv = *(const float4*)(gr + k);
      float4 bv = *(const float4*)(br + k);
      sg += wv.x * gv.x + wv.y * gv.y + wv.z * gv.z + wv.w * gv.w;
      sb += wv.x * bv.x + wv.y * bv.y + wv.z * bv.z + wv.w * bv.w;
    }
    Gp[kg * 1024 + n] = sg;
    Bp[kg * 1024 + n] = sb;
  } else if (fr < 1608) {    // dsum[l] = 1 + (-1)^l * cot(pi(2l+1)/2048)
    int l = (fr - 1600) * 64 + lane;
    float a = (float)(2 * l + 1) * 1.5339807878856412e-3f;  // pi/2048
    float cs = cosf(a), sn = sinf(a);
    float ct = cs / sn;
    dsum[l] = 1.0f + ((l & 1) ? -ct : ct);
  }
}

// ===================== prep2: reduce Gp/Bp partials -> Gv/Bv =====================
__global__ void fecam_prep2(const float* __restrict__ Gp, const float* __restrict__ Bp,
                            float* __restrict__ Gv, float* __restrict__ Bv) {
  int n = blockIdx.x * 256 + threadIdx.x;   // 0..1023
  Gv[n] = Gp[n] + Gp[1024 + n] + Gp[2048 + n] + Gp[3072 + n];
  Bv[n] = Bp[n] + Bp[1024 + n] + Bp[2048 + n] + Bp[3072 + n];
}

// ===================== prep1: W1D = (w1 . g) @ D, packed =====================
__global__ void fecam_prep1(const float* __restrict__ w1, const float* __restrict__ g,
                            const unsigned short* __restrict__ Dbf,
                            unsigned short* __restrict__ W1Dp) {
  __shared__ float Cl[4][16][132];
  const int tid = threadIdx.x;
  const int lane = tid & 63;
  const int wv = tid >> 6;
  const int l16 = lane & 15, lh = lane >> 4;
  const int bi = blockIdx.x * 4 + wv;      // 0..255
  const int n0 = (bi >> 2) * 16;
  const int l0 = (bi & 3) * 128;

  f32x4 acc[8];
#pragma unroll
  for (int jn = 0; jn < 8; ++jn) acc[jn] = (f32x4){0.f, 0.f, 0.f, 0.f};

  for (int ks = 0; ks < 16; ++ks) {
    int kbase = ks * 32 + lh * 8;
    const float* wr = w1 + (size_t)(n0 + l16) * 512 + kbase;
    float4 wa = *(const float4*)(wr);
    float4 wb = *(const float4*)(wr + 4);
    float4 ga = *(const float4*)(g + kbase);
    float4 gb = *(const float4*)(g + kbase + 4);
    bf16x8 af = pack4(cvt_pk_bf16(wa.x * ga.x, wa.y * ga.y),
                      cvt_pk_bf16(wa.z * ga.z, wa.w * ga.w),
                      cvt_pk_bf16(wb.x * gb.x, wb.y * gb.y),
                      cvt_pk_bf16(wb.z * gb.z, wb.w * gb.w));
#pragma unroll
    for (int jn = 0; jn < 8; ++jn) {
      bf16x8 bf = *(const bf16x8*)(Dbf + (((size_t)ks * 32 + (l0 >> 4) + jn) * 64 + lane) * 8);
      acc[jn] = __builtin_amdgcn_mfma_f32_16x16x32_bf16(af, bf, acc[jn], 0, 0, 0);
    }
  }
#pragma unroll
  for (int jn = 0; jn < 8; ++jn)
#pragma unroll
    for (int q = 0; q < 4; ++q) Cl[wv][lh * 4 + q][jn * 16 + l16] = acc[jn][q];
  __syncthreads();
#pragma unroll
  for (int ks2 = 0; ks2 < 4; ++ks2) {
    float v[8];
#pragma unroll
    for (int j = 0; j < 8; ++j) v[j] = Cl[wv][l16][ks2 * 32 + lh * 8 + j];
    unsigned short o[8];
#pragma unroll
    for (int j = 0; j < 8; j += 2) {
      unsigned pk = cvt_pk_bf16(v[j], v[j + 1]);
      o[j] = (unsigned short)pk;
      o[j + 1] = (unsigned short)(pk >> 16);
    }
    size_t idx = (((size_t)((l0 >> 5) + ks2) * 64 + (n0 >> 4)) * 64 + lane) * 8;
    *(u16x8*)(W1Dp + idx) = *(u16x8*)o;
  }
}

// ===================== fused main: R14 structure + continuous depth-2 B-prefetch
// (manual b0/b1 rotation, static names, even/odd unrolled body). =====================
__global__ __launch_bounds__(1024, 4) void fecam_main(
    const float* __restrict__ x, const float* __restrict__ gamma, const float* __restrict__ beta,
    const unsigned short* __restrict__ W1Dp, const unsigned short* __restrict__ w2p,
    const float* __restrict__ Gv, const float* __restrict__ Bv,
    const float* __restrict__ dsum, float* __restrict__ out) {
  extern __shared__ char smem[];
  char* bufA = smem;                     // 64KB: x frags -> h half1 frags
  char* bufB = smem + 65536;             // 64KB: h half0 frags
  float* ra = (float*)(smem + 131072);   // [64] sum x
  float* rb = ra + 64;                   // sum x^2
  float* rc = rb + 64;                   // sum x*dsum
  float* rs2 = rc + 64;                  // LN2 sums
  float* rq2 = rs2 + 64;                 // LN2 sumsq

  const int tid = threadIdx.x;
  const int lane = tid & 63;
  const int w = tid >> 6;            // wave 0..15
  const int l16 = lane & 15, lh = lane >> 4;
  const int b = blockIdx.x >> 3;
  const int c0 = (blockIdx.x & 7) * 64;

  if (tid < 320) ra[tid] = 0.0f;     // zero all 5 stat arrays
  __syncthreads();                   // bar0

  // ---- stage x -> bufA fragment-linear (wave w owns frag ks=w); row stats ----
  {
    const int cc = lane;             // row (c offset)
    const float* xb = x + ((size_t)b * 512) * 512 + c0 + cc;
    char* xwb = bufA + w * 4096 + (cc >> 4) * 1024 + (cc & 15) * 16;
    float s1 = 0.f, s2 = 0.f, sdp = 0.f;
#pragma unroll
    for (int gblk = 0; gblk < 4; ++gblk) {
      int k0 = w * 32 + gblk * 8;    // 8 consecutive k
      float4 d0 = *(const float4*)(dsum + k0);
      float4 d1 = *(const float4*)(dsum + k0 + 4);
      float v[8];
#pragma unroll
      for (int j = 0; j < 8; ++j) {
        v[j] = xb[(size_t)(k0 + j) * 512];
        s1 += v[j];
        s2 += v[j] * v[j];
      }
      sdp += v[0] * d0.x + v[1] * d0.y + v[2] * d0.z + v[3] * d0.w +
             v[4] * d1.x + v[5] * d1.y + v[6] * d1.z + v[7] * d1.w;
      unsigned short o[8];
#pragma unroll
      for (int j = 0; j < 8; j += 2) {
        unsigned pk = cvt_pk_bf16(v[j], v[j + 1]);
        o[j] = (unsigned short)pk;
        o[j + 1] = (unsigned short)(pk >> 16);
      }
      *(u16x8*)(xwb + gblk * 256) = *(u16x8*)o;
    }
    atomicAdd(&ra[cc], s1);
    atomicAdd(&rb[cc], s2);
    atomicAdd(&rc[cc], sdp);
  }

  // per-wave constants (direct loads — spill-free per R11/R14)
  float g_[2], b_[2], Gn_[2][2], Bn_[2][2];
#pragma unroll
  for (int jj = 0; jj < 2; ++jj) {
    g_[jj] = gamma[w * 32 + jj * 16 + l16];
    b_[jj] = beta[w * 32 + jj * 16 + l16];
  }
#pragma unroll
  for (int hh = 0; hh < 2; ++hh)
#pragma unroll
    for (int jj = 0; jj < 2; ++jj) {
      int n = hh * 512 + w * 32 + jj * 16 + l16;
      Gn_[hh][jj] = Gv[n];
      Bn_[hh][jj] = Bv[n];
    }

  __syncthreads();                   // bar1: x + stats visible

  const char* ards = smem + lane * 16;          // A-read base (x / h1 frags)
  const char* brds = bufB + lane * 16;          // A-read base (h0 frags)

  // ======== G2: two 512-col halves, wave = 64 rows x 32 cols ========
  // B-fragment base for this wave: elems; per-ks stride 64*64*8=32768, per-jj 512
#pragma unroll
  for (int half = 0; half < 2; ++half) {
    f32x4 acc2[4][2];
#pragma unroll
    for (int i = 0; i < 4; ++i)
#pragma unroll
      for (int jj = 0; jj < 2; ++jj) acc2[i][jj] = (f32x4){0.f, 0.f, 0.f, 0.f};

    const unsigned short* wb1 = W1Dp + ((size_t)(half * 32 + w * 2) * 64 + lane) * 8;
    bf16x8 b0[2], b1[2];
    b0[0] = *(const bf16x8*)(wb1);
    b0[1] = *(const bf16x8*)(wb1 + 512);

#pragma unroll
    for (int ks = 0; ks < 16; ks += 2) {
      // prefetch ks+1 into b1
      b1[0] = *(const bf16x8*)(wb1 + (size_t)(ks + 1) * 32768);
      b1[1] = *(const bf16x8*)(wb1 + (size_t)(ks + 1) * 32768 + 512);
      {
        bf16x8 af[4];
#pragma unroll
        for (int i = 0; i < 4; ++i)
          af[i] = *(const bf16x8*)(ards + (ks * 4 + i) * 1024);
#pragma unroll
        for (int i = 0; i < 4; ++i) {
          acc2[i][0] = __builtin_amdgcn_mfma_f32_16x16x32_bf16(af[i], b0[0], acc2[i][0], 0, 0, 0);
          acc2[i][1] = __builtin_amdgcn_mfma_f32_16x16x32_bf16(af[i], b0[1], acc2[i][1], 0, 0, 0);
        }
      }
      if (ks + 2 < 16) {
        b0[0] = *(const bf16x8*)(wb1 + (size_t)(ks + 2) * 32768);
        b0[1] = *(const bf16x8*)(wb1 + (size_t)(ks + 2) * 32768 + 512);
      }
      {
        bf16x8 af[4];
#pragma unroll
        for (int i = 0; i < 4; ++i)
          af[i] = *(const bf16x8*)(ards + ((ks + 1) * 4 + i) * 1024);
#pragma unroll
        for (int i = 0; i < 4; ++i) {
          acc2[i][0] = __builtin_amdgcn_mfma_f32_16x16x32_bf16(af[i], b1[0], acc2[i][0], 0, 0, 0);
          acc2[i][1] = __builtin_amdgcn_mfma_f32_16x16x32_bf16(af[i], b1[1], acc2[i][1], 0, 0, 0);
        }
      }
    }

    if (half == 1) __syncthreads();  // bar2: all x reads done before overwrite

    // h epilogue -> fragment-linear writes (frag ks = half*16 + w)
    char* hwb = (half ? bufA : bufB) + w * 4096 + (l16 >> 3) * 256 + lh * 64 + (l16 & 7) * 2;
    float mu_[4][4], rstd_[4][4];
#pragma unroll
    for (int i = 0; i < 4; ++i)
#pragma unroll
      for (int q = 0; q < 4; ++q) {
        int r = i * 16 + lh * 4 + q;
        float s1 = ra[r], s2v = rb[r];
        float mu = rc[r] * (1.0f / 512.0f);
        float var = s1 * s1 * (1.0f / 256.0f) + 2.0f * s2v - mu * mu;
        mu_[i][q] = mu;
        rstd_[i][q] = rsqrtf(var + 1e-6f);
      }
#pragma unroll
    for (int i = 0; i < 4; ++i)
#pragma unroll
      for (int jj = 0; jj < 2; ++jj)
#pragma unroll
        for (int q = 0; q < 4; ++q) {
          float c00 = fmaf(-rstd_[i][q] * mu_[i][q], Gn_[half][jj], Bn_[half][jj]);
          float v0 = fmaxf(fmaf(acc2[i][jj][q], rstd_[i][q], c00), 0.0f);
          *(unsigned short*)(hwb + i * 1024 + jj * 512 + q * 16) = bf16_rne(v0);
        }
  }
  __syncthreads();                   // bar3: h complete

  // ======== G3 (acc3 lives only from here): fw = h @ w2^T, K=1024 ========
  {
    f32x4 acc3[4][2];
#pragma unroll
    for (int i = 0; i < 4; ++i)
#pragma unroll
      for (int jj = 0; jj < 2; ++jj) acc3[i][jj] = (f32x4){0.f, 0.f, 0.f, 0.f};

    const unsigned short* wb2 = w2p + ((size_t)(w * 2) * 64 + lane) * 8;
    // per-ks stride = 32*64*8 = 16384 elems; second K-half offset = 16*16384
    bf16x8 b0[2], b1[2];
    b0[0] = *(const bf16x8*)(wb2);
    b0[1] = *(const bf16x8*)(wb2 + 512);

#pragma unroll
    for (int ks = 0; ks < 16; ks += 2) {
      b1[0] = *(const bf16x8*)(wb2 + (size_t)(ks + 1) * 16384);
      b1[1] = *(const bf16x8*)(wb2 + (size_t)(ks + 1) * 16384 + 512);
      {
        bf16x8 af[4];
#pragma unroll
        for (int i = 0; i < 4; ++i)
          af[i] = *(const bf16x8*)(brds + (ks * 4 + i) * 1024);
#pragma unroll
        for (int i = 0; i < 4; ++i) {
          acc3[i][0] = __builtin_amdgcn_mfma_f32_16x16x32_bf16(af[i], b0[0], acc3[i][0], 0, 0, 0);
          acc3[i][1] = __builtin_amdgcn_mfma_f32_16x16x32_bf16(af[i], b0[1], acc3[i][1], 0, 0, 0);
        }
      }
      b0[0] = *(const bf16x8*)(wb2 + (size_t)(ks + 2) * 16384);
      b0[1] = *(const bf16x8*)(wb2 + (size_t)(ks + 2) * 16384 + 512);
      {
        bf16x8 af[4];
#pragma unroll
        for (int i = 0; i < 4; ++i)
          af[i] = *(const bf16x8*)(brds + ((ks + 1) * 4 + i) * 1024);
#pragma unroll
        for (int i = 0; i < 4; ++i) {
          acc3[i][0] = __builtin_amdgcn_mfma_f32_16x16x32_bf16(af[i], b1[0], acc3[i][0], 0, 0, 0);
          acc3[i][1] = __builtin_amdgcn_mfma_f32_16x16x32_bf16(af[i], b1[1], acc3[i][1], 0, 0, 0);
        }
      }
    }
    // b0 now holds ks=16 (first frag of K-half 1) — continue seamlessly
#pragma unroll
    for (int ks = 16; ks < 32; ks += 2) {
      b1[0] = *(const bf16x8*)(wb2 + (size_t)(ks + 1) * 16384);
      b1[1] = *(const bf16x8*)(wb2 + (size_t)(ks + 1) * 16384 + 512);
      {
        bf16x8 af[4];
#pragma unroll
        for (int i = 0; i < 4; ++i)
          af[i] = *(const bf16x8*)(ards + ((ks - 16) * 4 + i) * 1024);
#pragma unroll
        for (int i = 0; i < 4; ++i) {
          acc3[i][0] = __builtin_amdgcn_mfma_f32_16x16x32_bf16(af[i], b0[0], acc3[i][0], 0, 0, 0);
          acc3[i][1] = __builtin_amdgcn_mfma_f32_16x16x32_bf16(af[i], b0[1], acc3[i][1], 0, 0, 0);
        }
      }
      if (ks + 2 < 32) {
        b0[0] = *(const bf16x8*)(wb2 + (size_t)(ks + 2) * 16384);
        b0[1] = *(const bf16x8*)(wb2 + (size_t)(ks + 2) * 16384 + 512);
      }
      {
        bf16x8 af[4];
#pragma unroll
        for (int i = 0; i < 4; ++i)
          af[i] = *(const bf16x8*)(ards + ((ks - 15) * 4 + i) * 1024);
#pragma unroll
        for (int i = 0; i < 4; ++i) {
          acc3[i][0] = __builtin_amdgcn_mfma_f32_16x16x32_bf16(af[i], b1[0], acc3[i][0], 0, 0, 0);
          acc3[i][1] = __builtin_amdgcn_mfma_f32_16x16x32_bf16(af[i], b1[1], acc3[i][1], 0, 0, 0);
        }
      }
    }

    // ---- sigmoid ----
#pragma unroll
    for (int i = 0; i < 4; ++i)
#pragma unroll
      for (int jj = 0; jj < 2; ++jj)
#pragma unroll
        for (int q = 0; q < 4; ++q)
          acc3[i][jj][q] = 1.0f / (1.0f + __expf(-acc3[i][jj][q]));

    // ---- LN2 stats ----
#pragma unroll
    for (int i = 0; i < 4; ++i) {
#pragma unroll
      for (int q = 0; q < 4; ++q) {
        float s = acc3[i][0][q] + acc3[i][1][q];
        float ss = acc3[i][0][q] * acc3[i][0][q] + acc3[i][1][q] * acc3[i][1][q];
#pragma unroll
        for (int m = 1; m <= 8; m <<= 1) {
          s += __shfl_xor(s, m);
          ss += __shfl_xor(ss, m);
        }
        if (l16 == 0) {
          atomicAdd(&rs2[i * 16 + lh * 4 + q], s);
          atomicAdd(&rq2[i * 16 + lh * 4 + q], ss);
        }
      }
    }
    __syncthreads();                 // bar4

    // ---- LN2 normalize, multiply by xp, store out[b][col][c0+r] ----
#pragma unroll
    for (int i = 0; i < 4; ++i) {
      float mu_[4], rstd_[4];
#pragma unroll
      for (int q = 0; q < 4; ++q) {
        int r = i * 16 + lh * 4 + q;
        float mu = rs2[r] * (1.0f / 512.0f);
        float var = rq2[r] * (1.0f / 512.0f) - mu * mu;
        mu_[q] = mu;
        rstd_[q] = rsqrtf(var + 1e-6f);
      }
#pragma unroll
      for (int jj = 0; jj < 2; ++jj) {
        int col = w * 32 + jj * 16 + l16;
        size_t base = ((size_t)b * 512 + col) * 512 + c0 + i * 16 + lh * 4;
        float4 xv = *(const float4*)(x + base);
        float4 ov;
#pragma unroll
        for (int q = 0; q < 4; ++q) {
          float fn = (acc3[i][jj][q] - mu_[q]) * rstd_[q] * g_[jj] + b_[jj];
          (&ov.x)[q] = (&xv.x)[q] * fn;
        }
        *(float4*)(out + base) = ov;
      }
    }
  }
}

extern "C" void kernel_launch(void* const* d_in, const int* in_sizes, int n_in,
                              void* d_out, int out_size, void* d_ws, size_t ws_size,
                              hipStream_t stream) {
  const float* x = (const float*)d_in[0];
  const float* gamma = (const float*)d_in[1];
  const float* beta = (const float*)d_in[2];
  const float* w1 = (const float*)d_in[3];
  const float* w2 = (const float*)d_in[4];

  unsigned short* w2p = (unsigned short*)d_ws;       // 524288 bf16
  unsigned short* W1Dp = w2p + 524288;               // 524288 bf16
  unsigned short* Dbf = W1Dp + 524288;               // 262144 bf16
  float* Gp = (float*)(Dbf + 262144);                // 4096 f32
  float* Bp = Gp + 4096;                             // 4096 f32
  float* dsum = Bp + 4096;                           // 512 f32
  float* Gv = dsum + 512;                            // 1024 f32
  float* Bv = Gv + 1024;                             // 1024 f32

  fecam_prep0<<<402, 256, 0, stream>>>(w1, w2, gamma, beta, Dbf, w2p, Gp, Bp, dsum);
  fecam_prep2<<<4, 256, 0, stream>>>(Gp, Bp, Gv, Bv);
  fecam_prep1<<<64, 256, 0, stream>>>(w1, gamma, Dbf, W1Dp);
  fecam_main<<<1024, 1024, 132416, stream>>>(x, gamma, beta, W1Dp, w2p, Gv, Bv, dsum,
                                             (float*)d_out);
}